// Round 13
// baseline (262.804 us; speedup 1.0000x reference)
//
#include <hip/hip_runtime.h>
#include <math.h>

#define NTP 256
#define NT 256      // main kernel threads; each block simulates TWO batch elements
#define NS 4096     // 2^12 amplitudes

typedef float f32x2 __attribute__((ext_vector_type(2)));

// CNOT ring: gates CNOT(i,(i+1)%12), wire j <-> bit (11-j).
// forward basis permutation pi(k), GF(2)-linear:
constexpr int ring_pi_c(int k) {
    int u = k ^ (k >> 1);
    u ^= u >> 2; u ^= u >> 4; u ^= u >> 8;
    int w0 = ((u >> 11) ^ u) & 1;
    return (u & 0x7FF) | (w0 << 11);
}
// inverse permutation sigma = pi^{-1}
constexpr int ring_sigma_c(int k) {
    int s = (k ^ (k >> 1)) & 0x3FF;
    int b10 = ((k >> 10) ^ (k >> 11) ^ k) & 1;
    int b11 = ((k >> 11) ^ k) & 1;
    return s | (b10 << 10) | (b11 << 11);
}
// storage swizzle (GF(2)-linear), proven benign conflicts; 32KB offset keeps bank map
constexpr int sig2(int m) { return m ^ ((m >> 4) & 0xF) ^ ((m >> 8) & 0xF); }

// real Y-rotation (c,s): a0' = c*a0 - s*a1 ; a1' = s*a0 + c*a1  (4 pk insts)
__device__ __forceinline__ void ygate(f32x2 cs_, f32x2& a0, f32x2& a1) {
    f32x2 n0, n1;
    asm("v_pk_mul_f32 %0, %3, %4 op_sel:[0,1] op_sel_hi:[1,1] neg_lo:[0,1] neg_hi:[0,1]\n\t"
        "v_pk_fma_f32 %0, %2, %4, %0 op_sel:[0,0,0] op_sel_hi:[1,0,1]\n\t"
        "v_pk_mul_f32 %1, %2, %4 op_sel:[0,1] op_sel_hi:[1,1]\n\t"
        "v_pk_fma_f32 %1, %3, %4, %1 op_sel:[0,0,0] op_sel_hi:[1,0,1]"
        : "=&v"(n0), "=&v"(n1)
        : "v"(a0), "v"(a1), "v"(cs_));
    a0 = n0; a1 = n1;
}

// diagonal cmul: a = (p+iq)*(x+iy), e=(p,q)  (2 pk insts)
__device__ __forceinline__ void cdiag(f32x2 e, f32x2& a) {
    f32x2 m;
    asm("v_pk_mul_f32 %0, %1, %2 op_sel:[1,1] op_sel_hi:[0,1] neg_lo:[1,0]\n\t"
        "v_pk_fma_f32 %0, %1, %2, %0 op_sel:[0,0,0] op_sel_hi:[1,0,1]"
        : "=&v"(m) : "v"(a), "v"(e));
    a = m;
}

template<int P>
__device__ __forceinline__ void ygate_on_bit(f32x2 a[16], float2 cs_) {
    f32x2 v = f32x2{cs_.x, cs_.y};
    #pragma unroll
    for (int r = 0; r < 16; ++r)
        if (!(r & (1 << P)))
            ygate(v, a[r], a[r | (1 << P)]);
}

__device__ __forceinline__ void ygates4(f32x2 a[16], const float2* __restrict__ yrow, int o) {
    ygate_on_bit<3>(a, yrow[o + 0]);
    ygate_on_bit<2>(a, yrow[o + 1]);
    ygate_on_bit<1>(a, yrow[o + 2]);
    ygate_on_bit<0>(a, yrow[o + 3]);
}

// ---- prep1: encode cos/sin + ZYZ decomposition of the 72 fused gates
__global__ void prep1_kernel(const float* __restrict__ x,     // (B,24)
                             const float* __restrict__ wts,   // (6,3,12)
                             float2* __restrict__ ys,         // 72 (cy,sy)
                             float2* __restrict__ cdah,       // 72 (c/2, d/2)
                             float2* __restrict__ cs,         // B*24
                             int total)
{
    int idx = blockIdx.x * blockDim.x + threadIdx.x;
    if (idx < total) {
        float th = 0.5f * x[idx];
        float s, c; sincosf(th, &s, &c);
        cs[idx] = make_float2(c, s);
    }
    if (idx < 72) {
        int ab = idx / 12, w = idx % 12;
        float a  = 0.5f * wts[(ab * 3 + 0) * 12 + w];
        float bb = 0.5f * wts[(ab * 3 + 1) * 12 + w];
        float g  = 0.5f * wts[(ab * 3 + 2) * 12 + w];
        float sa, ca, sb, cb, sg, cg;
        sincosf(a,  &sa, &ca);
        sincosf(bb, &sb, &cb);
        sincosf(g,  &sg, &cg);
        float A = cb * (ca * cg - sa * sg);   // U = Ry(g)Rz(2b)Ry(a) in ABCD form
        float B = sb * (ca * cg + sa * sg);
        float C = cb * (sa * cg + ca * sg);
        float D = sb * (sa * cg - ca * sg);
        // exact ZYZ: U = Rz(c)·Ry(t)·Rz(d); cy=cos(t/2)=|U00|, sy=sin(t/2)=|U10|
        float cy = sqrtf(A * A + B * B);
        float sy = sqrtf(C * C + D * D);
        float f00 = atan2f(-B, A);            // phase of U00 = A - iB
        float f10 = atan2f(D, C);             // phase of U10 = C + iD
        ys[idx]   = make_float2(cy, sy);
        cdah[idx] = make_float2(0.5f * (f10 - f00), -0.5f * (f10 + f00)); // (c/2, d/2)
    }
}

// ---- prep2: 7 diagonal tables E_l(k) (batch-independent)
__global__ void prep2_kernel(const float2* __restrict__ cdah,
                             float2* __restrict__ tabs)       // 7*4096
{
    int idx = blockIdx.x * blockDim.x + threadIdx.x;
    if (idx >= 7 * NS) return;
    int tl = idx >> 12, k = idx & (NS - 1);
    int sk = ring_sigma_c(k);
    const float QP = 0.7853981633974483f;   // pi/4
    float ph = 0.f;
    for (int w = 0; w < 12; ++w) {
        float zd = ((k  >> (11 - w)) & 1) ? 1.f : -1.f;
        float zc = ((sk >> (11 - w)) & 1) ? 1.f : -1.f;
        float dcf, ccf;
        if (tl == 3)      { dcf = QP;                       ccf = cdah[2 * 12 + w].x; }
        else if (tl == 4) { dcf = cdah[3 * 12 + w].y - QP;  ccf = 0.f; }
        else {
            int ald = (tl < 3) ? tl : tl - 1;
            dcf = cdah[ald * 12 + w].y;
            ccf = (tl == 0) ? 0.f : cdah[((tl < 3) ? tl - 1 : tl - 2) * 12 + w].x;
        }
        ph += zd * dcf + zc * ccf;
    }
    float s, c; sincosf(ph, &s, &c);
    tabs[idx] = make_float2(c, s);
}

// write-only product-state init into one psi buffer
__device__ __forceinline__ void init_psi(f32x2* __restrict__ p, const float2* __restrict__ csb,
                                         int t, int tb) {
    float2 rc[12];
    #pragma unroll
    for (int i = 0; i < 12; ++i) rc[i] = csb[i];
    float mlo = 1.f;
    #pragma unroll
    for (int bit = 0; bit < 8; ++bit)
        mlo *= ((t >> bit) & 1) ? rc[11 - bit].y : rc[11 - bit].x;
    int pct = __popc(t);
    #pragma unroll
    for (int r = 0; r < 16; ++r) {
        float mhi = 1.f;
        #pragma unroll
        for (int q = 0; q < 4; ++q)
            mhi *= ((r >> q) & 1) ? rc[3 - q].y : rc[3 - q].x;
        float mag = mhi * mlo;
        int pc = (pct + __popc(r)) & 3;
        f32x2 v;
        v.x = (pc == 0) ? mag : ((pc == 2) ? -mag : 0.f);
        v.y = (pc == 1) ? -mag : ((pc == 3) ? mag : 0.f);
        p[(r << 8) | (tb ^ r)] = v;
    }
}

__global__ __launch_bounds__(NT, 1)   // (N,1): proven natural-allocation/no-spill regime
void tqhea_kernel(const float2* __restrict__ ys,    // 72 (cy,sy)
                  const float2* __restrict__ cs,    // (B,24)
                  const f32x2*  __restrict__ tabs,  // 7*4096 diagonal tables
                  float* __restrict__ out)          // (B,1)
{
    __shared__ f32x2 psi[2][NS];     // 64 KB: two elements, sig2-swizzled

    const int b0 = blockIdx.x << 1;
    const int t  = threadIdx.x;

    const int lo = t & 0xF, h = t >> 4;
    const int tb     = (t & 0xF0) | (lo ^ h);          // P0: addr = (r<<8)|(tb^r)
    const int baseP1 = (h << 8) | (lo ^ h);            // P1: addr = baseP1 ^ 17r
    const int baseP2 = (t << 4) | (lo ^ h);            // P2: addr = baseP2 ^ r
    const int Qt     = sig2(ring_pi_c(t << 4));        // ring scatter: Qt ^ sig2(pi(r))
    const int Pt     = ring_pi_c(t << 4);              // reduction diag

    const float2* cs_0  = cs + b0 * 24;
    const float2* cs_1  = cs_0 + 24;
    const float2* cs12_0 = cs_0 + 12;
    const float2* cs12_1 = cs_1 + 12;

    // ---- init both elements (write-only passes)
    init_psi(psi[0], cs_0, t, tb);
    init_psi(psi[1], cs_1, t, tb);

    // prefetch layer-0 diagonal table (shared by both elements)
    f32x2 e[16];
    #pragma unroll
    for (int r = 0; r < 16; ++r) e[r] = tabs[(r << 8) | t];
    __syncthreads();

    float acc0 = 0.f, acc1 = 0.f;

    #pragma unroll 1
    for (int lay = 0; lay < 7; ++lay) {
        const bool isx = (lay == 3);
        const float2* yrow0 = isx ? cs12_0 : ys + ((lay < 3) ? lay : lay - 1) * 12;
        const float2* yrow1 = isx ? cs12_1 : yrow0;
        f32x2 a0[16], a1[16];

        // ---- P0: wires 0..3 (k bits 11..8 reg-local); diagonal first; in-place per-thread
        #pragma unroll
        for (int r = 0; r < 16; ++r) a0[r] = psi[0][(r << 8) | (tb ^ r)];
        #pragma unroll
        for (int r = 0; r < 16; ++r) a1[r] = psi[1][(r << 8) | (tb ^ r)];
        #pragma unroll
        for (int r = 0; r < 16; ++r) cdiag(e[r], a0[r]);
        ygates4(a0, yrow0, 0);
        #pragma unroll
        for (int r = 0; r < 16; ++r) psi[0][(r << 8) | (tb ^ r)] = a0[r];
        #pragma unroll
        for (int r = 0; r < 16; ++r) cdiag(e[r], a1[r]);
        ygates4(a1, yrow1, 0);
        #pragma unroll
        for (int r = 0; r < 16; ++r) psi[1][(r << 8) | (tb ^ r)] = a1[r];
        __syncthreads();

        // ---- P1: wires 4..7; in-place per-thread
        #pragma unroll
        for (int r = 0; r < 16; ++r) a0[r] = psi[0][baseP1 ^ (17 * r)];
        #pragma unroll
        for (int r = 0; r < 16; ++r) a1[r] = psi[1][baseP1 ^ (17 * r)];
        ygates4(a0, yrow0, 4);
        #pragma unroll
        for (int r = 0; r < 16; ++r) psi[0][baseP1 ^ (17 * r)] = a0[r];
        ygates4(a1, yrow1, 4);
        #pragma unroll
        for (int r = 0; r < 16; ++r) psi[1][baseP1 ^ (17 * r)] = a1[r];
        __syncthreads();

        // ---- P2: wires 8..11; thread t, reg r hold k=(t<<4)|r
        #pragma unroll
        for (int r = 0; r < 16; ++r) a0[r] = psi[0][baseP2 ^ r];
        #pragma unroll
        for (int r = 0; r < 16; ++r) a1[r] = psi[1][baseP2 ^ r];
        if (lay < 6) {      // prefetch next layer's table; hidden under P2 compute+barriers
            const f32x2* Tn = tabs + (lay + 1) * NS;
            #pragma unroll
            for (int r = 0; r < 16; ++r) e[r] = Tn[(r << 8) | t];
        }
        ygates4(a0, yrow0, 8);
        if (lay == 6) {
            ygates4(a1, yrow1, 8);
            // ---- <H>: final ring via pi; diag = 12 - 2*popc(pi(k))
            #pragma unroll
            for (int r = 0; r < 16; ++r) {
                float d = 12.0f - 2.0f * (float)__popc(Pt ^ ring_pi_c(r));
                acc0 += (a0[r].x * a0[r].x + a0[r].y * a0[r].y) * d;
                acc1 += (a1[r].x * a1[r].x + a1[r].y * a1[r].y) * d;
            }
        } else if (isx) {
            // in-place (no ring), per-thread
            #pragma unroll
            for (int r = 0; r < 16; ++r) psi[0][baseP2 ^ r] = a0[r];
            ygates4(a1, yrow1, 8);
            #pragma unroll
            for (int r = 0; r < 16; ++r) psi[1][baseP2 ^ r] = a1[r];
            __syncthreads();
        } else {
            __syncthreads();    // WAR: all reads of both buffers before ring scatter
            #pragma unroll
            for (int r = 0; r < 16; ++r) psi[0][Qt ^ sig2(ring_pi_c(r))] = a0[r];
            ygates4(a1, yrow1, 8);
            #pragma unroll
            for (int r = 0; r < 16; ++r) psi[1][Qt ^ sig2(ring_pi_c(r))] = a1[r];
            __syncthreads();
        }
    }

    // ---- reduce: wave shfl, then cross-wave via psi reuse
    #pragma unroll
    for (int off = 32; off > 0; off >>= 1) {
        acc0 += __shfl_down(acc0, off);
        acc1 += __shfl_down(acc1, off);
    }
    __syncthreads();                       // all psi reads done; safe to reuse
    if ((t & 63) == 0) {
        ((float*)psi)[t >> 6]     = acc0;
        ((float*)psi)[4 + (t >> 6)] = acc1;
    }
    __syncthreads();
    if (t == 0) {
        const float* rb = (const float*)psi;
        out[b0]     = rb[0] + rb[1] + rb[2] + rb[3];
        out[b0 + 1] = rb[4] + rb[5] + rb[6] + rb[7];
    }
}

extern "C" void kernel_launch(void* const* d_in, const int* in_sizes, int n_in,
                              void* d_out, int out_size, void* d_ws, size_t ws_size,
                              hipStream_t stream) {
    const float* x   = (const float*)d_in[0];   // (B, 24) float32
    const float* wts = (const float*)d_in[1];   // (6, 3, 12) float32
    float* out = (float*)d_out;                 // (B, 1) float32
    int B = in_sizes[0] / 24;
    int total = B * 24;

    char* ws = (char*)d_ws;
    float2* ys   = (float2*)(ws);                         // 576 B
    float2* cdah = (float2*)(ws + 576);                   // 576 B
    float2* cs   = (float2*)(ws + 1152);                  // B*24*8
    float2* tabs = (float2*)(ws + 1152 + (size_t)total * 8);  // 7*4096*8

    prep1_kernel<<<dim3((total + NTP - 1) / NTP), dim3(NTP), 0, stream>>>(x, wts, ys, cdah, cs, total);
    prep2_kernel<<<dim3((7 * NS + NTP - 1) / NTP), dim3(NTP), 0, stream>>>(cdah, tabs);
    tqhea_kernel<<<dim3(B / 2), dim3(NT), 0, stream>>>(ys, cs, (const f32x2*)tabs, out);
}

// Round 15
// 193.094 us; speedup vs baseline: 1.3610x; 1.3610x over previous
//
#include <hip/hip_runtime.h>
#include <math.h>

#define NTP 256
#define NT 512      // 8 waves/block, one batch element per block, 8 amps/thread
#define NS 4096     // 2^12 amplitudes

typedef float f32x2 __attribute__((ext_vector_type(2)));

// CNOT ring permutation pi(k) (GF(2)-linear), wire j <-> bit (11-j)
constexpr int ring_pi_c(int k) {
    int u = k ^ (k >> 1);
    u ^= u >> 2; u ^= u >> 4; u ^= u >> 8;
    int w0 = ((u >> 11) ^ u) & 1;
    return (u & 0x7FF) | (w0 << 11);
}
constexpr int ring_sigma_c(int k) {     // pi^{-1}, used by prep2
    int s = (k ^ (k >> 1)) & 0x3FF;
    int b10 = ((k >> 10) ^ (k >> 11) ^ k) & 1;
    int b11 = ((k >> 11) ^ k) & 1;
    return s | (b10 << 10) | (b11 << 11);
}
// storage swizzle: s = k ^ (k4 | k5<<1 | k6<<2 | (k4^k6)<<3)
// bank-conflict-free (bijective t[3:0]->s[3:0] per 16-lane group) for
// P0/P1/P2/P3 reads+writes AND the ring scatter; trivial on bits {0..2,11}.
constexpr int swz(int k) {
    int e4 = (k >> 4) & 1, e5 = (k >> 5) & 1, e6 = (k >> 6) & 1;
    return k ^ (e4 | (e5 << 1) | (e6 << 2) | ((e4 ^ e6) << 3));
}

// real Y-rotation (c,s): a0' = c*a0 - s*a1 ; a1' = s*a0 + c*a1  (4 pk insts)
__device__ __forceinline__ void ygate(f32x2 cs_, f32x2& a0, f32x2& a1) {
    f32x2 n0, n1;
    asm("v_pk_mul_f32 %0, %3, %4 op_sel:[0,1] op_sel_hi:[1,1] neg_lo:[0,1] neg_hi:[0,1]\n\t"
        "v_pk_fma_f32 %0, %2, %4, %0 op_sel:[0,0,0] op_sel_hi:[1,0,1]\n\t"
        "v_pk_mul_f32 %1, %2, %4 op_sel:[0,1] op_sel_hi:[1,1]\n\t"
        "v_pk_fma_f32 %1, %3, %4, %1 op_sel:[0,0,0] op_sel_hi:[1,0,1]"
        : "=&v"(n0), "=&v"(n1)
        : "v"(a0), "v"(a1), "v"(cs_));
    a0 = n0; a1 = n1;
}

// diagonal cmul: a = (p+iq)*(x+iy), e=(p,q)  (2 pk insts)
__device__ __forceinline__ void cdiag(f32x2 e, f32x2& a) {
    f32x2 m;
    asm("v_pk_mul_f32 %0, %1, %2 op_sel:[1,1] op_sel_hi:[0,1] neg_lo:[1,0]\n\t"
        "v_pk_fma_f32 %0, %1, %2, %0 op_sel:[0,0,0] op_sel_hi:[1,0,1]"
        : "=&v"(m) : "v"(a), "v"(e));
    a = m;
}

template<int P>
__device__ __forceinline__ void ygate8(f32x2 a[8], float2 cs_) {
    f32x2 v = f32x2{cs_.x, cs_.y};
    #pragma unroll
    for (int r = 0; r < 8; ++r)
        if (!(r & (1 << P)))
            ygate(v, a[r], a[r | (1 << P)]);
}

// ---- prep1: encode cos/sin + ZYZ decomposition of the 72 fused gates
__global__ void prep1_kernel(const float* __restrict__ x,
                             const float* __restrict__ wts,
                             float2* __restrict__ ys,         // 72 (cy,sy)
                             float2* __restrict__ cdah,       // 72 (c/2, d/2)
                             float2* __restrict__ cs,         // B*24
                             int total)
{
    int idx = blockIdx.x * blockDim.x + threadIdx.x;
    if (idx < total) {
        float th = 0.5f * x[idx];
        float s, c; sincosf(th, &s, &c);
        cs[idx] = make_float2(c, s);
    }
    if (idx < 72) {
        int ab = idx / 12, w = idx % 12;
        float a  = 0.5f * wts[(ab * 3 + 0) * 12 + w];
        float bb = 0.5f * wts[(ab * 3 + 1) * 12 + w];
        float g  = 0.5f * wts[(ab * 3 + 2) * 12 + w];
        float sa, ca, sb, cb, sg, cg;
        sincosf(a,  &sa, &ca);
        sincosf(bb, &sb, &cb);
        sincosf(g,  &sg, &cg);
        float A = cb * (ca * cg - sa * sg);
        float B = sb * (ca * cg + sa * sg);
        float C = cb * (sa * cg + ca * sg);
        float D = sb * (sa * cg - ca * sg);
        float cy = sqrtf(A * A + B * B);
        float sy = sqrtf(C * C + D * D);
        float f00 = atan2f(-B, A);
        float f10 = atan2f(D, C);
        ys[idx]   = make_float2(cy, sy);
        cdah[idx] = make_float2(0.5f * (f10 - f00), -0.5f * (f10 + f00));
    }
}

// ---- prep2: 7 diagonal tables E_l(k), applied at P0 of layer l
__global__ void prep2_kernel(const float2* __restrict__ cdah,
                             float2* __restrict__ tabs)       // 7*4096
{
    int idx = blockIdx.x * blockDim.x + threadIdx.x;
    if (idx >= 7 * NS) return;
    int tl = idx >> 12, k = idx & (NS - 1);
    int sk = ring_sigma_c(k);
    const float QP = 0.7853981633974483f;   // pi/4
    float ph = 0.f;
    for (int w = 0; w < 12; ++w) {
        float zd = ((k  >> (11 - w)) & 1) ? 1.f : -1.f;
        float zc = ((sk >> (11 - w)) & 1) ? 1.f : -1.f;
        float dcf, ccf;
        if (tl == 3)      { dcf = QP;                       ccf = cdah[2 * 12 + w].x; }
        else if (tl == 4) { dcf = cdah[3 * 12 + w].y - QP;  ccf = 0.f; }
        else {
            int ald = (tl < 3) ? tl : tl - 1;
            dcf = cdah[ald * 12 + w].y;
            ccf = (tl == 0) ? 0.f : cdah[((tl < 3) ? tl - 1 : tl - 2) * 12 + w].x;
        }
        ph += zd * dcf + zc * ccf;
    }
    float s, c; sincosf(ph, &s, &c);
    tabs[idx] = make_float2(c, s);
}

// Phase maps (thread t: 9 bits, reg r: 3 bits):
// P0: k=(r<<9)|t               wires 0,1,2
// P1: k=t[8:6]<<9|r<<6|t[5:0]  wires 3,4,5
// P2: k=t[8:3]<<6|r<<3|t[2:0]  wires 6,7,8
// P3: k=(t<<3)|r               wires 9,10,11; ring folded into P3 scatter
__global__ __launch_bounds__(NT, 1)
void tqhea_kernel(const float2* __restrict__ ys,    // 72 (cy,sy)
                  const float2* __restrict__ cs,    // (B,24)
                  const f32x2*  __restrict__ tabs,  // 7*4096 diag tables
                  float* __restrict__ out)          // (B,1)
{
    __shared__ f32x2 psi[NS];        // 32 KB, swz-swizzled

    const int b = blockIdx.x;
    const int t = threadIdx.x;       // 0..511

    const int tsw = swz(t);                          // P0: idx = (r<<9)|tsw
    const int sQt = swz(ring_pi_c(t << 3));          // scatter: idx = sQt ^ pi(r)
    const int Pt  = ring_pi_c(t << 3);               // reduction diag base

    const float2* csb  = cs + b * 24;
    const float2* cs12 = csb + 12;

    // ---- init: |0..0> + first RX layer = product state (write-only, P0 map)
    {
        float2 rc[12];
        #pragma unroll
        for (int i = 0; i < 12; ++i) rc[i] = csb[i];
        float mlan = 1.f;
        #pragma unroll
        for (int bit = 0; bit < 9; ++bit)            // t bit b <-> wire 11-b
            mlan *= ((t >> bit) & 1) ? rc[11 - bit].y : rc[11 - bit].x;
        int q = __popc(t);
        #pragma unroll
        for (int r = 0; r < 8; ++r) {
            float mr = 1.f;
            #pragma unroll
            for (int p = 0; p < 3; ++p)              // r bit p <-> wire 2-p
                mr *= ((r >> p) & 1) ? rc[2 - p].y : rc[2 - p].x;
            float mag = mr * mlan;
            int pc = (q + __popc(r)) & 3;            // (-i)^popcount phase
            f32x2 v;
            v.x = (pc == 0) ? mag : ((pc == 2) ? -mag : 0.f);
            v.y = (pc == 1) ? -mag : ((pc == 3) ? mag : 0.f);
            psi[(r << 9) | tsw] = v;
        }
    }
    __syncthreads();

    float acc = 0.f;

    #pragma unroll 1
    for (int lay = 0; lay < 7; ++lay) {
        const bool isx = (lay == 3);
        const float2* yrow = isx ? cs12 : ys + ((lay < 3) ? lay : lay - 1) * 12;
        f32x2 a[8], e[8];

        // ---- P0: wires 0..2 reg-local; diagonal table first
        #pragma unroll
        for (int r = 0; r < 8; ++r) e[r] = tabs[lay * NS + (r << 9) + t];
        #pragma unroll
        for (int r = 0; r < 8; ++r) a[r] = psi[(r << 9) | tsw];
        #pragma unroll
        for (int r = 0; r < 8; ++r) cdiag(e[r], a[r]);
        ygate8<2>(a, yrow[0]);
        ygate8<1>(a, yrow[1]);
        ygate8<0>(a, yrow[2]);
        #pragma unroll
        for (int r = 0; r < 8; ++r) psi[(r << 9) | tsw] = a[r];
        __syncthreads();

        // ---- P1: wires 3..5
        int a1[8];
        #pragma unroll
        for (int r = 0; r < 8; ++r)
            a1[r] = swz(((t >> 6) << 9) | (r << 6) | (t & 63));
        #pragma unroll
        for (int r = 0; r < 8; ++r) a[r] = psi[a1[r]];
        ygate8<2>(a, yrow[3]);
        ygate8<1>(a, yrow[4]);
        ygate8<0>(a, yrow[5]);
        #pragma unroll
        for (int r = 0; r < 8; ++r) psi[a1[r]] = a[r];
        __syncthreads();

        // ---- P2: wires 6..8
        int a2[8];
        #pragma unroll
        for (int r = 0; r < 8; ++r)
            a2[r] = swz(((t >> 3) << 6) | (r << 3) | (t & 7));
        #pragma unroll
        for (int r = 0; r < 8; ++r) a[r] = psi[a2[r]];
        ygate8<2>(a, yrow[6]);
        ygate8<1>(a, yrow[7]);
        ygate8<0>(a, yrow[8]);
        #pragma unroll
        for (int r = 0; r < 8; ++r) psi[a2[r]] = a[r];
        __syncthreads();

        // ---- P3: wires 9..11; thread t, reg r hold k=(t<<3)|r
        const int base3 = swz(t << 3);               // a3[r] = base3 ^ r
        #pragma unroll
        for (int r = 0; r < 8; ++r) a[r] = psi[base3 ^ r];
        ygate8<2>(a, yrow[9]);
        ygate8<1>(a, yrow[10]);
        ygate8<0>(a, yrow[11]);
        if (lay == 6) {
            // ---- <H>: final ring via pi; diag = 12 - 2*popc(pi(k));
            //      FULL ring_pi_c(r) (includes bit-11 parity row) — R14 bug was pi3(r)
            #pragma unroll
            for (int r = 0; r < 8; ++r) {
                float d = 12.0f - 2.0f * (float)__popc(Pt ^ ring_pi_c(r));
                acc += (a[r].x * a[r].x + a[r].y * a[r].y) * d;
            }
        } else if (isx) {
            #pragma unroll
            for (int r = 0; r < 8; ++r) psi[base3 ^ r] = a[r];   // in-place, no ring
            __syncthreads();
        } else {
            __syncthreads();    // WAR: all P3 reads complete before ring scatter
            // swz is identity on pi(r)'s support bits {0..2,11} -> idx = sQt ^ pi(r)
            #pragma unroll
            for (int r = 0; r < 8; ++r) psi[sQt ^ ring_pi_c(r)] = a[r];
            __syncthreads();
        }
    }

    // ---- reduce: per-wave shfl, cross-wave via psi reuse
    #pragma unroll
    for (int off = 32; off > 0; off >>= 1)
        acc += __shfl_down(acc, off);
    __syncthreads();                       // all psi reads done; safe to reuse
    if ((t & 63) == 0) ((float*)psi)[t >> 6] = acc;
    __syncthreads();
    if (t == 0) {
        const float* rb = (const float*)psi;
        out[b] = rb[0] + rb[1] + rb[2] + rb[3] + rb[4] + rb[5] + rb[6] + rb[7];
    }
}

extern "C" void kernel_launch(void* const* d_in, const int* in_sizes, int n_in,
                              void* d_out, int out_size, void* d_ws, size_t ws_size,
                              hipStream_t stream) {
    const float* x   = (const float*)d_in[0];   // (B, 24) float32
    const float* wts = (const float*)d_in[1];   // (6, 3, 12) float32
    float* out = (float*)d_out;                 // (B, 1) float32
    int B = in_sizes[0] / 24;
    int total = B * 24;

    char* ws = (char*)d_ws;
    float2* ys   = (float2*)(ws);                         // 576 B
    float2* cdah = (float2*)(ws + 576);                   // 576 B
    float2* cs   = (float2*)(ws + 1152);                  // B*24*8
    float2* tabs = (float2*)(ws + 1152 + (size_t)total * 8);  // 7*4096*8

    prep1_kernel<<<dim3((total + NTP - 1) / NTP), dim3(NTP), 0, stream>>>(x, wts, ys, cdah, cs, total);
    prep2_kernel<<<dim3((7 * NS + NTP - 1) / NTP), dim3(NTP), 0, stream>>>(cdah, tabs);
    tqhea_kernel<<<dim3(B), dim3(NT), 0, stream>>>(ys, cs, (const f32x2*)tabs, out);
}

// Round 16
// 189.518 us; speedup vs baseline: 1.3867x; 1.0189x over previous
//
#include <hip/hip_runtime.h>
#include <math.h>

#define NTP 256
#define NT 512      // 8 waves/block, one batch element per block, 8 amps/thread
#define NS 4096     // 2^12 amplitudes

typedef float f32x2 __attribute__((ext_vector_type(2)));

// CNOT ring permutation pi(k) (GF(2)-linear), wire j <-> bit (11-j)
constexpr int ring_pi_c(int k) {
    int u = k ^ (k >> 1);
    u ^= u >> 2; u ^= u >> 4; u ^= u >> 8;
    int w0 = ((u >> 11) ^ u) & 1;
    return (u & 0x7FF) | (w0 << 11);
}
constexpr int ring_sigma_c(int k) {     // pi^{-1}, used by prep2
    int s = (k ^ (k >> 1)) & 0x3FF;
    int b10 = ((k >> 10) ^ (k >> 11) ^ k) & 1;
    int b11 = ((k >> 11) ^ k) & 1;
    return s | (b10 << 10) | (b11 << 11);
}
// storage swizzle: s = k ^ (k4 | k5<<1 | k6<<2 | (k4^k6)<<3)
// bank-conflict-free for P0/P1/P2/P3 reads+writes AND the ring scatter;
// identity on bits 7..11 -> preserves the k[11:9] wave-slice ownership.
constexpr int swz(int k) {
    int e4 = (k >> 4) & 1, e5 = (k >> 5) & 1, e6 = (k >> 6) & 1;
    return k ^ (e4 | (e5 << 1) | (e6 << 2) | ((e4 ^ e6) << 3));
}

// real Y-rotation (c,s): a0' = c*a0 - s*a1 ; a1' = s*a0 + c*a1  (4 pk insts)
__device__ __forceinline__ void ygate(f32x2 cs_, f32x2& a0, f32x2& a1) {
    f32x2 n0, n1;
    asm("v_pk_mul_f32 %0, %3, %4 op_sel:[0,1] op_sel_hi:[1,1] neg_lo:[0,1] neg_hi:[0,1]\n\t"
        "v_pk_fma_f32 %0, %2, %4, %0 op_sel:[0,0,0] op_sel_hi:[1,0,1]\n\t"
        "v_pk_mul_f32 %1, %2, %4 op_sel:[0,1] op_sel_hi:[1,1]\n\t"
        "v_pk_fma_f32 %1, %3, %4, %1 op_sel:[0,0,0] op_sel_hi:[1,0,1]"
        : "=&v"(n0), "=&v"(n1)
        : "v"(a0), "v"(a1), "v"(cs_));
    a0 = n0; a1 = n1;
}

// diagonal cmul: a = (p+iq)*(x+iy), e=(p,q)  (2 pk insts)
__device__ __forceinline__ void cdiag(f32x2 e, f32x2& a) {
    f32x2 m;
    asm("v_pk_mul_f32 %0, %1, %2 op_sel:[1,1] op_sel_hi:[0,1] neg_lo:[1,0]\n\t"
        "v_pk_fma_f32 %0, %1, %2, %0 op_sel:[0,0,0] op_sel_hi:[1,0,1]"
        : "=&v"(m) : "v"(a), "v"(e));
    a = m;
}

template<int P>
__device__ __forceinline__ void ygate8(f32x2 a[8], float2 cs_) {
    f32x2 v = f32x2{cs_.x, cs_.y};
    #pragma unroll
    for (int r = 0; r < 8; ++r)
        if (!(r & (1 << P)))
            ygate(v, a[r], a[r | (1 << P)]);
}

// intra-wave LDS fence: drains this wave's DS ops; "memory" stops the compiler
// from hoisting the following ds_reads above the preceding ds_writes.
__device__ __forceinline__ void wave_lds_fence() {
    asm volatile("s_waitcnt lgkmcnt(0)" ::: "memory");
}

// ---- prep1: encode cos/sin + ZYZ decomposition of the 72 fused gates
__global__ void prep1_kernel(const float* __restrict__ x,
                             const float* __restrict__ wts,
                             float2* __restrict__ ys,         // 72 (cy,sy)
                             float2* __restrict__ cdah,       // 72 (c/2, d/2)
                             float2* __restrict__ cs,         // B*24
                             int total)
{
    int idx = blockIdx.x * blockDim.x + threadIdx.x;
    if (idx < total) {
        float th = 0.5f * x[idx];
        float s, c; sincosf(th, &s, &c);
        cs[idx] = make_float2(c, s);
    }
    if (idx < 72) {
        int ab = idx / 12, w = idx % 12;
        float a  = 0.5f * wts[(ab * 3 + 0) * 12 + w];
        float bb = 0.5f * wts[(ab * 3 + 1) * 12 + w];
        float g  = 0.5f * wts[(ab * 3 + 2) * 12 + w];
        float sa, ca, sb, cb, sg, cg;
        sincosf(a,  &sa, &ca);
        sincosf(bb, &sb, &cb);
        sincosf(g,  &sg, &cg);
        float A = cb * (ca * cg - sa * sg);
        float B = sb * (ca * cg + sa * sg);
        float C = cb * (sa * cg + ca * sg);
        float D = sb * (sa * cg - ca * sg);
        float cy = sqrtf(A * A + B * B);
        float sy = sqrtf(C * C + D * D);
        float f00 = atan2f(-B, A);
        float f10 = atan2f(D, C);
        ys[idx]   = make_float2(cy, sy);
        cdah[idx] = make_float2(0.5f * (f10 - f00), -0.5f * (f10 + f00));
    }
}

// ---- prep2: 7 diagonal tables E_l(k), applied at P0 of layer l
__global__ void prep2_kernel(const float2* __restrict__ cdah,
                             float2* __restrict__ tabs)       // 7*4096
{
    int idx = blockIdx.x * blockDim.x + threadIdx.x;
    if (idx >= 7 * NS) return;
    int tl = idx >> 12, k = idx & (NS - 1);
    int sk = ring_sigma_c(k);
    const float QP = 0.7853981633974483f;   // pi/4
    float ph = 0.f;
    for (int w = 0; w < 12; ++w) {
        float zd = ((k  >> (11 - w)) & 1) ? 1.f : -1.f;
        float zc = ((sk >> (11 - w)) & 1) ? 1.f : -1.f;
        float dcf, ccf;
        if (tl == 3)      { dcf = QP;                       ccf = cdah[2 * 12 + w].x; }
        else if (tl == 4) { dcf = cdah[3 * 12 + w].y - QP;  ccf = 0.f; }
        else {
            int ald = (tl < 3) ? tl : tl - 1;
            dcf = cdah[ald * 12 + w].y;
            ccf = (tl == 0) ? 0.f : cdah[((tl < 3) ? tl - 1 : tl - 2) * 12 + w].x;
        }
        ph += zd * dcf + zc * ccf;
    }
    float s, c; sincosf(ph, &s, &c);
    tabs[idx] = make_float2(c, s);
}

// Phase maps (thread t: 9 bits, reg r: 3 bits):
// P0: k=(r<<9)|t               wires 0,1,2   (cross-wave writes -> barrier)
// P1: k=t[8:6]<<9|r<<6|t[5:0]  wires 3,4,5   (wave-private -> lgkm fence only)
// P2: k=t[8:3]<<6|r<<3|t[2:0]  wires 6,7,8   (wave-private -> lgkm fence only)
// P3: k=(t<<3)|r               wires 9,10,11; ring scatter cross-wave -> barriers
__global__ __launch_bounds__(NT, 1)
void tqhea_kernel(const float2* __restrict__ ys,    // 72 (cy,sy)
                  const float2* __restrict__ cs,    // (B,24)
                  const f32x2*  __restrict__ tabs,  // 7*4096 diag tables
                  float* __restrict__ out)          // (B,1)
{
    __shared__ f32x2 psi[NS];        // 32 KB, swz-swizzled

    const int b = blockIdx.x;
    const int t = threadIdx.x;       // 0..511

    const int tsw = swz(t);                          // P0: idx = (r<<9)|tsw
    const int sQt = swz(ring_pi_c(t << 3));          // scatter: idx = sQt ^ pi(r)
    const int Pt  = ring_pi_c(t << 3);               // reduction diag base

    const float2* csb  = cs + b * 24;
    const float2* cs12 = csb + 12;

    // ---- init: |0..0> + first RX layer = product state (write-only, P0 map)
    {
        float2 rc[12];
        #pragma unroll
        for (int i = 0; i < 12; ++i) rc[i] = csb[i];
        float mlan = 1.f;
        #pragma unroll
        for (int bit = 0; bit < 9; ++bit)            // t bit b <-> wire 11-b
            mlan *= ((t >> bit) & 1) ? rc[11 - bit].y : rc[11 - bit].x;
        int q = __popc(t);
        #pragma unroll
        for (int r = 0; r < 8; ++r) {
            float mr = 1.f;
            #pragma unroll
            for (int p = 0; p < 3; ++p)              // r bit p <-> wire 2-p
                mr *= ((r >> p) & 1) ? rc[2 - p].y : rc[2 - p].x;
            float mag = mr * mlan;
            int pc = (q + __popc(r)) & 3;            // (-i)^popcount phase
            f32x2 v;
            v.x = (pc == 0) ? mag : ((pc == 2) ? -mag : 0.f);
            v.y = (pc == 1) ? -mag : ((pc == 3) ? mag : 0.f);
            psi[(r << 9) | tsw] = v;
        }
    }
    __syncthreads();

    float acc = 0.f;

    #pragma unroll 1
    for (int lay = 0; lay < 7; ++lay) {
        const bool isx = (lay == 3);
        const float2* yrow = isx ? cs12 : ys + ((lay < 3) ? lay : lay - 1) * 12;
        f32x2 a[8], e[8];

        // ---- P0: wires 0..2 reg-local; diagonal table first
        #pragma unroll
        for (int r = 0; r < 8; ++r) e[r] = tabs[lay * NS + (r << 9) + t];
        #pragma unroll
        for (int r = 0; r < 8; ++r) a[r] = psi[(r << 9) | tsw];
        #pragma unroll
        for (int r = 0; r < 8; ++r) cdiag(e[r], a[r]);
        ygate8<2>(a, yrow[0]);
        ygate8<1>(a, yrow[1]);
        ygate8<0>(a, yrow[2]);
        #pragma unroll
        for (int r = 0; r < 8; ++r) psi[(r << 9) | tsw] = a[r];
        __syncthreads();                 // P0 writes are cross-wave-slice: full barrier

        // ---- P1: wires 3..5 (wave-private slice k[11:9]=t[8:6]; swz preserves it)
        int a1[8];
        #pragma unroll
        for (int r = 0; r < 8; ++r)
            a1[r] = swz(((t >> 6) << 9) | (r << 6) | (t & 63));
        #pragma unroll
        for (int r = 0; r < 8; ++r) a[r] = psi[a1[r]];
        ygate8<2>(a, yrow[3]);
        ygate8<1>(a, yrow[4]);
        ygate8<0>(a, yrow[5]);
        #pragma unroll
        for (int r = 0; r < 8; ++r) psi[a1[r]] = a[r];
        wave_lds_fence();                // intra-wave only: no block barrier needed

        // ---- P2: wires 6..8 (wave-private)
        int a2[8];
        #pragma unroll
        for (int r = 0; r < 8; ++r)
            a2[r] = swz(((t >> 3) << 6) | (r << 3) | (t & 7));
        #pragma unroll
        for (int r = 0; r < 8; ++r) a[r] = psi[a2[r]];
        ygate8<2>(a, yrow[6]);
        ygate8<1>(a, yrow[7]);
        ygate8<0>(a, yrow[8]);
        #pragma unroll
        for (int r = 0; r < 8; ++r) psi[a2[r]] = a[r];
        wave_lds_fence();                // intra-wave only

        // ---- P3: wires 9..11; thread t, reg r hold k=(t<<3)|r
        const int base3 = swz(t << 3);               // a3[r] = base3 ^ r
        #pragma unroll
        for (int r = 0; r < 8; ++r) a[r] = psi[base3 ^ r];
        ygate8<2>(a, yrow[9]);
        ygate8<1>(a, yrow[10]);
        ygate8<0>(a, yrow[11]);
        if (lay == 6) {
            // ---- <H>: final ring via pi; diag = 12 - 2*popc(pi(k))
            #pragma unroll
            for (int r = 0; r < 8; ++r) {
                float d = 12.0f - 2.0f * (float)__popc(Pt ^ ring_pi_c(r));
                acc += (a[r].x * a[r].x + a[r].y * a[r].y) * d;
            }
        } else if (isx) {
            #pragma unroll
            for (int r = 0; r < 8; ++r) psi[base3 ^ r] = a[r];   // in-place, no ring
            __syncthreads();             // next P0 reads cross-slice
        } else {
            __syncthreads();    // WAR: all waves' P3 reads done before ring scatter
            // swz is identity on pi(r)'s support bits {0..2,11} -> idx = sQt ^ pi(r)
            #pragma unroll
            for (int r = 0; r < 8; ++r) psi[sQt ^ ring_pi_c(r)] = a[r];
            __syncthreads();
        }
    }

    // ---- reduce: per-wave shfl, cross-wave via psi reuse
    #pragma unroll
    for (int off = 32; off > 0; off >>= 1)
        acc += __shfl_down(acc, off);
    __syncthreads();                       // all psi reads done; safe to reuse
    if ((t & 63) == 0) ((float*)psi)[t >> 6] = acc;
    __syncthreads();
    if (t == 0) {
        const float* rb = (const float*)psi;
        out[b] = rb[0] + rb[1] + rb[2] + rb[3] + rb[4] + rb[5] + rb[6] + rb[7];
    }
}

extern "C" void kernel_launch(void* const* d_in, const int* in_sizes, int n_in,
                              void* d_out, int out_size, void* d_ws, size_t ws_size,
                              hipStream_t stream) {
    const float* x   = (const float*)d_in[0];   // (B, 24) float32
    const float* wts = (const float*)d_in[1];   // (6, 3, 12) float32
    float* out = (float*)d_out;                 // (B, 1) float32
    int B = in_sizes[0] / 24;
    int total = B * 24;

    char* ws = (char*)d_ws;
    float2* ys   = (float2*)(ws);                         // 576 B
    float2* cdah = (float2*)(ws + 576);                   // 576 B
    float2* cs   = (float2*)(ws + 1152);                  // B*24*8
    float2* tabs = (float2*)(ws + 1152 + (size_t)total * 8);  // 7*4096*8

    prep1_kernel<<<dim3((total + NTP - 1) / NTP), dim3(NTP), 0, stream>>>(x, wts, ys, cdah, cs, total);
    prep2_kernel<<<dim3((7 * NS + NTP - 1) / NTP), dim3(NTP), 0, stream>>>(cdah, tabs);
    tqhea_kernel<<<dim3(B), dim3(NT), 0, stream>>>(ys, cs, (const f32x2*)tabs, out);
}

// Round 17
// 185.635 us; speedup vs baseline: 1.4157x; 1.0209x over previous
//
#include <hip/hip_runtime.h>
#include <math.h>

#define NTP 256
#define NT 512      // 8 waves/block, one batch element per block, 8 amps/thread
#define NS 4096     // 2^12 amplitudes

typedef float f32x2 __attribute__((ext_vector_type(2)));

// CNOT ring permutation pi(k) (GF(2)-linear), wire j <-> bit (11-j)
constexpr int ring_pi_c(int k) {
    int u = k ^ (k >> 1);
    u ^= u >> 2; u ^= u >> 4; u ^= u >> 8;
    int w0 = ((u >> 11) ^ u) & 1;
    return (u & 0x7FF) | (w0 << 11);
}
constexpr int ring_sigma_c(int k) {     // pi^{-1}, used by prep2
    int s = (k ^ (k >> 1)) & 0x3FF;
    int b10 = ((k >> 10) ^ (k >> 11) ^ k) & 1;
    int b11 = ((k >> 11) ^ k) & 1;
    return s | (b10 << 10) | (b11 << 11);
}
// storage swizzle: s = k ^ (k4 | k5<<1 | k6<<2 | (k4^k6)<<3)
// bank-conflict-free for P0/P1/P2/P3 reads+writes AND the ring scatter;
// identity on bits 7..11 -> preserves the k[11:9] wave-slice ownership.
constexpr int swz(int k) {
    int e4 = (k >> 4) & 1, e5 = (k >> 5) & 1, e6 = (k >> 6) & 1;
    return k ^ (e4 | (e5 << 1) | (e6 << 2) | ((e4 ^ e6) << 3));
}

// real Y-rotation (c,s): a0' = c*a0 - s*a1 ; a1' = s*a0 + c*a1  (4 pk insts)
__device__ __forceinline__ void ygate(f32x2 cs_, f32x2& a0, f32x2& a1) {
    f32x2 n0, n1;
    asm("v_pk_mul_f32 %0, %3, %4 op_sel:[0,1] op_sel_hi:[1,1] neg_lo:[0,1] neg_hi:[0,1]\n\t"
        "v_pk_fma_f32 %0, %2, %4, %0 op_sel:[0,0,0] op_sel_hi:[1,0,1]\n\t"
        "v_pk_mul_f32 %1, %2, %4 op_sel:[0,1] op_sel_hi:[1,1]\n\t"
        "v_pk_fma_f32 %1, %3, %4, %1 op_sel:[0,0,0] op_sel_hi:[1,0,1]"
        : "=&v"(n0), "=&v"(n1)
        : "v"(a0), "v"(a1), "v"(cs_));
    a0 = n0; a1 = n1;
}

// full complex gate G = [[A-iB, -C+iD],[C+iD, A+iB]], ab=(A,B), cd=(C,D) (8 pk)
__device__ __forceinline__ void app1p(f32x2 ab, f32x2 cd, f32x2& a0, f32x2& a1) {
    f32x2 n0, n1;
    asm("v_pk_mul_f32 %0, %2, %4 op_sel:[0,0] op_sel_hi:[1,0]\n\t"
        "v_pk_fma_f32 %0, %2, %4, %0 op_sel:[1,1,0] op_sel_hi:[0,1,1] neg_hi:[0,1,0]\n\t"
        "v_pk_fma_f32 %0, %3, %5, %0 op_sel:[0,0,0] op_sel_hi:[1,0,1] neg_lo:[0,1,0] neg_hi:[0,1,0]\n\t"
        "v_pk_fma_f32 %0, %3, %5, %0 op_sel:[1,1,0] op_sel_hi:[0,1,1] neg_lo:[0,1,0]\n\t"
        "v_pk_mul_f32 %1, %3, %4 op_sel:[0,0] op_sel_hi:[1,0]\n\t"
        "v_pk_fma_f32 %1, %3, %4, %1 op_sel:[1,1,0] op_sel_hi:[0,1,1] neg_lo:[0,1,0]\n\t"
        "v_pk_fma_f32 %1, %2, %5, %1 op_sel:[0,0,0] op_sel_hi:[1,0,1]\n\t"
        "v_pk_fma_f32 %1, %2, %5, %1 op_sel:[1,1,0] op_sel_hi:[0,1,1] neg_lo:[0,1,0]"
        : "=&v"(n0), "=&v"(n1)
        : "v"(a0), "v"(a1), "v"(ab), "v"(cd));
    a0 = n0; a1 = n1;
}

// diagonal cmul: a = (p+iq)*(x+iy), e=(p,q)  (2 pk insts)
__device__ __forceinline__ void cdiag(f32x2 e, f32x2& a) {
    f32x2 m;
    asm("v_pk_mul_f32 %0, %1, %2 op_sel:[1,1] op_sel_hi:[0,1] neg_lo:[1,0]\n\t"
        "v_pk_fma_f32 %0, %1, %2, %0 op_sel:[0,0,0] op_sel_hi:[1,0,1]"
        : "=&v"(m) : "v"(a), "v"(e));
    a = m;
}

template<int P>
__device__ __forceinline__ void ygate8(f32x2 a[8], float2 cs_) {
    f32x2 v = f32x2{cs_.x, cs_.y};
    #pragma unroll
    for (int r = 0; r < 8; ++r)
        if (!(r & (1 << P)))
            ygate(v, a[r], a[r | (1 << P)]);
}
template<int P>
__device__ __forceinline__ void cgate8(f32x2 a[8], f32x2 gab, f32x2 gcd) {
    #pragma unroll
    for (int r = 0; r < 8; ++r)
        if (!(r & (1 << P)))
            app1p(gab, gcd, a[r], a[r | (1 << P)]);
}

// intra-wave LDS fence
__device__ __forceinline__ void wave_lds_fence() {
    asm volatile("s_waitcnt lgkmcnt(0)" ::: "memory");
}

// layer-3 gate: U3' = U_3 * RX(x[12+w])  (ABCD closed form, proven R7)
__device__ __forceinline__ void load_gate3(const float4* __restrict__ U3w,
                                           const float2* __restrict__ cs12,
                                           int w, f32x2& ab, f32x2& cd) {
    float4 g = U3w[w];
    float2 sc = cs12[w];
    float c = sc.x, s = sc.y;
    float A = g.x * c + g.w * s;
    float B = g.y * c - g.z * s;
    float C = g.z * c + g.y * s;
    float D = g.w * c - g.x * s;
    ab = f32x2{A, B}; cd = f32x2{C, D};
}

// ---- prep1: encode cos/sin + ZYZ of ansatz blocks (+ raw ABCD of block 3)
__global__ void prep1_kernel(const float* __restrict__ x,
                             const float* __restrict__ wts,
                             float2* __restrict__ ys,         // 72 (cy,sy); row 3 unused
                             float2* __restrict__ cdah,       // 72 (c/2, d/2); row 3 unused
                             float4* __restrict__ U3w,        // 12 ABCD of block 3
                             float2* __restrict__ cs,         // B*24
                             int total)
{
    int idx = blockIdx.x * blockDim.x + threadIdx.x;
    if (idx < total) {
        float th = 0.5f * x[idx];
        float s, c; sincosf(th, &s, &c);
        cs[idx] = make_float2(c, s);
    }
    if (idx < 72) {
        int ab = idx / 12, w = idx % 12;
        float a  = 0.5f * wts[(ab * 3 + 0) * 12 + w];
        float bb = 0.5f * wts[(ab * 3 + 1) * 12 + w];
        float g  = 0.5f * wts[(ab * 3 + 2) * 12 + w];
        float sa, ca, sb, cb, sg, cg;
        sincosf(a,  &sa, &ca);
        sincosf(bb, &sb, &cb);
        sincosf(g,  &sg, &cg);
        float A = cb * (ca * cg - sa * sg);
        float B = sb * (ca * cg + sa * sg);
        float C = cb * (sa * cg + ca * sg);
        float D = sb * (sa * cg - ca * sg);
        if (ab == 3) U3w[w] = make_float4(A, B, C, D);
        float cy = sqrtf(A * A + B * B);
        float sy = sqrtf(C * C + D * D);
        float f00 = atan2f(-B, A);
        float f10 = atan2f(D, C);
        ys[idx]   = make_float2(cy, sy);
        cdah[idx] = make_float2(0.5f * (f10 - f00), -0.5f * (f10 + f00));
    }
}

// ---- prep2: 6 diagonal tables E_l(k), applied at P0 of layer l
// E_0=D0; E_1=D1*C0(sig); E_2=D2*C1(sig); E_3=C2(sig) (layer3 = full ABCD gate);
// E_4=D4; E_5=D5*C4(sig); C5 vanishes in |.|^2
__global__ void prep2_kernel(const float2* __restrict__ cdah,
                             float2* __restrict__ tabs)       // 6*4096
{
    int idx = blockIdx.x * blockDim.x + threadIdx.x;
    if (idx >= 6 * NS) return;
    int tl = idx >> 12, k = idx & (NS - 1);
    int sk = ring_sigma_c(k);
    float ph = 0.f;
    for (int w = 0; w < 12; ++w) {
        float zd = ((k  >> (11 - w)) & 1) ? 1.f : -1.f;
        float zc = ((sk >> (11 - w)) & 1) ? 1.f : -1.f;
        float dcf = 0.f, ccf = 0.f;
        if (tl == 0)      { dcf = cdah[0 * 12 + w].y; }
        else if (tl == 1) { dcf = cdah[1 * 12 + w].y; ccf = cdah[0 * 12 + w].x; }
        else if (tl == 2) { dcf = cdah[2 * 12 + w].y; ccf = cdah[1 * 12 + w].x; }
        else if (tl == 3) { ccf = cdah[2 * 12 + w].x; }
        else if (tl == 4) { dcf = cdah[4 * 12 + w].y; }
        else              { dcf = cdah[5 * 12 + w].y; ccf = cdah[4 * 12 + w].x; }
        ph += zd * dcf + zc * ccf;
    }
    float s, c; sincosf(ph, &s, &c);
    tabs[idx] = make_float2(c, s);
}

// Phase maps (thread t: 9 bits, reg r: 3 bits):
// P0: k=(r<<9)|t               wires 0,1,2   (cross-wave -> barrier)
// P1: k=t[8:6]<<9|r<<6|t[5:0]  wires 3,4,5   (wave-private -> fence)
// P2: k=t[8:3]<<6|r<<3|t[2:0]  wires 6,7,8   (wave-private -> fence)
// P3: k=(t<<3)|r               wires 9,10,11; ring scatter (cross-wave -> barriers)
__global__ __launch_bounds__(NT, 1)
void tqhea_kernel(const float2* __restrict__ ys,    // 72 (cy,sy)
                  const float2* __restrict__ cs,    // (B,24)
                  const f32x2*  __restrict__ tabs,  // 6*4096 diag tables
                  const float4* __restrict__ U3w,   // 12 ABCD (block 3)
                  float* __restrict__ out)          // (B,1)
{
    __shared__ f32x2 psi[NS];        // 32 KB, swz-swizzled

    const int b = blockIdx.x;
    const int t = threadIdx.x;       // 0..511

    const int tsw = swz(t);                          // P0: idx = (r<<9)|tsw
    const int sQt = swz(ring_pi_c(t << 3));          // scatter: idx = sQt ^ pi(r)
    const int Pt  = ring_pi_c(t << 3);               // reduction diag base

    const float2* csb  = cs + b * 24;
    const float2* cs12 = csb + 12;

    // ---- init: |0..0> + first RX layer = product state (write-only, P0 map)
    {
        float2 rc[12];
        #pragma unroll
        for (int i = 0; i < 12; ++i) rc[i] = csb[i];
        float mlan = 1.f;
        #pragma unroll
        for (int bit = 0; bit < 9; ++bit)            // t bit b <-> wire 11-b
            mlan *= ((t >> bit) & 1) ? rc[11 - bit].y : rc[11 - bit].x;
        int q = __popc(t);
        #pragma unroll
        for (int r = 0; r < 8; ++r) {
            float mr = 1.f;
            #pragma unroll
            for (int p = 0; p < 3; ++p)              // r bit p <-> wire 2-p
                mr *= ((r >> p) & 1) ? rc[2 - p].y : rc[2 - p].x;
            float mag = mr * mlan;
            int pc = (q + __popc(r)) & 3;            // (-i)^popcount phase
            f32x2 v;
            v.x = (pc == 0) ? mag : ((pc == 2) ? -mag : 0.f);
            v.y = (pc == 1) ? -mag : ((pc == 3) ? mag : 0.f);
            psi[(r << 9) | tsw] = v;
        }
    }

    // preload layer-0 diagonal table
    f32x2 e[8];
    #pragma unroll
    for (int r = 0; r < 8; ++r) e[r] = tabs[(r << 9) + t];
    __syncthreads();

    float acc = 0.f;

    #pragma unroll 1
    for (int lay = 0; lay < 6; ++lay) {
        const bool full = (lay == 3);                // block 3 = full ABCD gates (RX folded)
        const float2* yrow = ys + lay * 12;
        f32x2 a[8];

        // ---- P0: wires 0..2; diagonal first, then prefetch next layer's table
        #pragma unroll
        for (int r = 0; r < 8; ++r) a[r] = psi[(r << 9) | tsw];
        #pragma unroll
        for (int r = 0; r < 8; ++r) cdiag(e[r], a[r]);
        if (lay < 5) {
            #pragma unroll
            for (int r = 0; r < 8; ++r) e[r] = tabs[(lay + 1) * NS + (r << 9) + t];
        }
        if (full) {
            f32x2 gab, gcd;
            load_gate3(U3w, cs12, 0, gab, gcd); cgate8<2>(a, gab, gcd);
            load_gate3(U3w, cs12, 1, gab, gcd); cgate8<1>(a, gab, gcd);
            load_gate3(U3w, cs12, 2, gab, gcd); cgate8<0>(a, gab, gcd);
        } else {
            ygate8<2>(a, yrow[0]);
            ygate8<1>(a, yrow[1]);
            ygate8<0>(a, yrow[2]);
        }
        #pragma unroll
        for (int r = 0; r < 8; ++r) psi[(r << 9) | tsw] = a[r];
        __syncthreads();                 // P0 writes are cross-wave-slice

        // ---- P1: wires 3..5 (wave-private)
        int a1[8];
        #pragma unroll
        for (int r = 0; r < 8; ++r)
            a1[r] = swz(((t >> 6) << 9) | (r << 6) | (t & 63));
        #pragma unroll
        for (int r = 0; r < 8; ++r) a[r] = psi[a1[r]];
        if (full) {
            f32x2 gab, gcd;
            load_gate3(U3w, cs12, 3, gab, gcd); cgate8<2>(a, gab, gcd);
            load_gate3(U3w, cs12, 4, gab, gcd); cgate8<1>(a, gab, gcd);
            load_gate3(U3w, cs12, 5, gab, gcd); cgate8<0>(a, gab, gcd);
        } else {
            ygate8<2>(a, yrow[3]);
            ygate8<1>(a, yrow[4]);
            ygate8<0>(a, yrow[5]);
        }
        #pragma unroll
        for (int r = 0; r < 8; ++r) psi[a1[r]] = a[r];
        wave_lds_fence();

        // ---- P2: wires 6..8 (wave-private)
        int a2[8];
        #pragma unroll
        for (int r = 0; r < 8; ++r)
            a2[r] = swz(((t >> 3) << 6) | (r << 3) | (t & 7));
        #pragma unroll
        for (int r = 0; r < 8; ++r) a[r] = psi[a2[r]];
        if (full) {
            f32x2 gab, gcd;
            load_gate3(U3w, cs12, 6, gab, gcd); cgate8<2>(a, gab, gcd);
            load_gate3(U3w, cs12, 7, gab, gcd); cgate8<1>(a, gab, gcd);
            load_gate3(U3w, cs12, 8, gab, gcd); cgate8<0>(a, gab, gcd);
        } else {
            ygate8<2>(a, yrow[6]);
            ygate8<1>(a, yrow[7]);
            ygate8<0>(a, yrow[8]);
        }
        #pragma unroll
        for (int r = 0; r < 8; ++r) psi[a2[r]] = a[r];
        wave_lds_fence();

        // ---- P3: wires 9..11; thread t, reg r hold k=(t<<3)|r
        const int base3 = swz(t << 3);               // a3[r] = base3 ^ r
        #pragma unroll
        for (int r = 0; r < 8; ++r) a[r] = psi[base3 ^ r];
        if (full) {
            f32x2 gab, gcd;
            load_gate3(U3w, cs12, 9,  gab, gcd); cgate8<2>(a, gab, gcd);
            load_gate3(U3w, cs12, 10, gab, gcd); cgate8<1>(a, gab, gcd);
            load_gate3(U3w, cs12, 11, gab, gcd); cgate8<0>(a, gab, gcd);
        } else {
            ygate8<2>(a, yrow[9]);
            ygate8<1>(a, yrow[10]);
            ygate8<0>(a, yrow[11]);
        }
        if (lay == 5) {
            // ---- <H>: final ring via pi; diag = 12 - 2*popc(pi(k))
            #pragma unroll
            for (int r = 0; r < 8; ++r) {
                float d = 12.0f - 2.0f * (float)__popc(Pt ^ ring_pi_c(r));
                acc += (a[r].x * a[r].x + a[r].y * a[r].y) * d;
            }
        } else {
            __syncthreads();    // WAR: all waves' P3 reads done before ring scatter
            #pragma unroll
            for (int r = 0; r < 8; ++r) psi[sQt ^ ring_pi_c(r)] = a[r];
            __syncthreads();
        }
    }

    // ---- reduce: per-wave shfl, cross-wave via psi reuse
    #pragma unroll
    for (int off = 32; off > 0; off >>= 1)
        acc += __shfl_down(acc, off);
    __syncthreads();                       // all psi reads done; safe to reuse
    if ((t & 63) == 0) ((float*)psi)[t >> 6] = acc;
    __syncthreads();
    if (t == 0) {
        const float* rb = (const float*)psi;
        out[b] = rb[0] + rb[1] + rb[2] + rb[3] + rb[4] + rb[5] + rb[6] + rb[7];
    }
}

extern "C" void kernel_launch(void* const* d_in, const int* in_sizes, int n_in,
                              void* d_out, int out_size, void* d_ws, size_t ws_size,
                              hipStream_t stream) {
    const float* x   = (const float*)d_in[0];   // (B, 24) float32
    const float* wts = (const float*)d_in[1];   // (6, 3, 12) float32
    float* out = (float*)d_out;                 // (B, 1) float32
    int B = in_sizes[0] / 24;
    int total = B * 24;

    char* ws = (char*)d_ws;
    float2* ys   = (float2*)(ws);                         // 576 B
    float2* cdah = (float2*)(ws + 576);                   // 576 B
    float4* U3w  = (float4*)(ws + 1152);                  // 192 B
    float2* cs   = (float2*)(ws + 1344);                  // B*24*8
    float2* tabs = (float2*)(ws + 1344 + (size_t)total * 8);  // 6*4096*8

    prep1_kernel<<<dim3((total + NTP - 1) / NTP), dim3(NTP), 0, stream>>>(x, wts, ys, cdah, U3w, cs, total);
    prep2_kernel<<<dim3((6 * NS + NTP - 1) / NTP), dim3(NTP), 0, stream>>>(cdah, tabs);
    tqhea_kernel<<<dim3(B), dim3(NT), 0, stream>>>(ys, cs, (const f32x2*)tabs, U3w, out);
}

// Round 20
// 184.705 us; speedup vs baseline: 1.4228x; 1.0050x over previous
//
#include <hip/hip_runtime.h>
#include <math.h>

#define NTP 256
#define NT 512      // 8 waves/block, one batch element per block, 8 amps/thread
#define NS 4096     // 2^12 amplitudes

typedef float f32x2 __attribute__((ext_vector_type(2)));

// CNOT ring permutation pi(k) (GF(2)-linear), wire j <-> bit (11-j)
constexpr int ring_pi_c(int k) {
    int u = k ^ (k >> 1);
    u ^= u >> 2; u ^= u >> 4; u ^= u >> 8;
    int w0 = ((u >> 11) ^ u) & 1;
    return (u & 0x7FF) | (w0 << 11);
}
constexpr int ring_sigma_c(int k) {     // pi^{-1}, used by prep2
    int s = (k ^ (k >> 1)) & 0x3FF;
    int b10 = ((k >> 10) ^ (k >> 11) ^ k) & 1;
    int b11 = ((k >> 11) ^ k) & 1;
    return s | (b10 << 10) | (b11 << 11);
}
// storage swizzle: s = k ^ (k4 | k5<<1 | k6<<2 | (k4^k6)<<3); GF(2)-linear.
// bank-conflict-free for P0/P1/P2/P3 reads+writes AND the ring scatter;
// identity on bits 7..11 -> preserves wave-slice ownership.
constexpr int swz(int k) {
    int e4 = (k >> 4) & 1, e5 = (k >> 5) & 1, e6 = (k >> 6) & 1;
    return k ^ (e4 | (e5 << 1) | (e6 << 2) | ((e4 ^ e6) << 3));
}

// real Y-rotation (c,s): a0' = c*a0 - s*a1 ; a1' = s*a0 + c*a1  (4 pk insts)
__device__ __forceinline__ void ygate(f32x2 cs_, f32x2& a0, f32x2& a1) {
    f32x2 n0, n1;
    asm("v_pk_mul_f32 %0, %3, %4 op_sel:[0,1] op_sel_hi:[1,1] neg_lo:[0,1] neg_hi:[0,1]\n\t"
        "v_pk_fma_f32 %0, %2, %4, %0 op_sel:[0,0,0] op_sel_hi:[1,0,1]\n\t"
        "v_pk_mul_f32 %1, %2, %4 op_sel:[0,1] op_sel_hi:[1,1]\n\t"
        "v_pk_fma_f32 %1, %3, %4, %1 op_sel:[0,0,0] op_sel_hi:[1,0,1]"
        : "=&v"(n0), "=&v"(n1)
        : "v"(a0), "v"(a1), "v"(cs_));
    a0 = n0; a1 = n1;
}

// full complex gate G = [[A-iB, -C+iD],[C+iD, A+iB]], ab=(A,B), cd=(C,D) (8 pk)
__device__ __forceinline__ void app1p(f32x2 ab, f32x2 cd, f32x2& a0, f32x2& a1) {
    f32x2 n0, n1;
    asm("v_pk_mul_f32 %0, %2, %4 op_sel:[0,0] op_sel_hi:[1,0]\n\t"
        "v_pk_fma_f32 %0, %2, %4, %0 op_sel:[1,1,0] op_sel_hi:[0,1,1] neg_hi:[0,1,0]\n\t"
        "v_pk_fma_f32 %0, %3, %5, %0 op_sel:[0,0,0] op_sel_hi:[1,0,1] neg_lo:[0,1,0] neg_hi:[0,1,0]\n\t"
        "v_pk_fma_f32 %0, %3, %5, %0 op_sel:[1,1,0] op_sel_hi:[0,1,1] neg_lo:[0,1,0]\n\t"
        "v_pk_mul_f32 %1, %3, %4 op_sel:[0,0] op_sel_hi:[1,0]\n\t"
        "v_pk_fma_f32 %1, %3, %4, %1 op_sel:[1,1,0] op_sel_hi:[0,1,1] neg_lo:[0,1,0]\n\t"
        "v_pk_fma_f32 %1, %2, %5, %1 op_sel:[0,0,0] op_sel_hi:[1,0,1]\n\t"
        "v_pk_fma_f32 %1, %2, %5, %1 op_sel:[1,1,0] op_sel_hi:[0,1,1] neg_lo:[0,1,0]"
        : "=&v"(n0), "=&v"(n1)
        : "v"(a0), "v"(a1), "v"(ab), "v"(cd));
    a0 = n0; a1 = n1;
}

// diagonal cmul: a = (p+iq)*(x+iy), e=(p,q)  (2 pk insts)
__device__ __forceinline__ void cdiag(f32x2 e, f32x2& a) {
    f32x2 m;
    asm("v_pk_mul_f32 %0, %1, %2 op_sel:[1,1] op_sel_hi:[0,1] neg_lo:[1,0]\n\t"
        "v_pk_fma_f32 %0, %1, %2, %0 op_sel:[0,0,0] op_sel_hi:[1,0,1]"
        : "=&v"(m) : "v"(a), "v"(e));
    a = m;
}

template<int P>
__device__ __forceinline__ void ygate8(f32x2 a[8], float2 cs_) {
    f32x2 v = f32x2{cs_.x, cs_.y};
    #pragma unroll
    for (int r = 0; r < 8; ++r)
        if (!(r & (1 << P)))
            ygate(v, a[r], a[r | (1 << P)]);
}
template<int P>
__device__ __forceinline__ void cgate8(f32x2 a[8], f32x2 gab, f32x2 gcd) {
    #pragma unroll
    for (int r = 0; r < 8; ++r)
        if (!(r & (1 << P)))
            app1p(gab, gcd, a[r], a[r | (1 << P)]);
}

// intra-wave LDS fence
__device__ __forceinline__ void wave_lds_fence() {
    asm volatile("s_waitcnt lgkmcnt(0)" ::: "memory");
}

// priority hint around pure-VALU gate clusters (T5): favor math-phase waves
__device__ __forceinline__ void prio_hi() { __builtin_amdgcn_s_setprio(1); }
__device__ __forceinline__ void prio_lo() { __builtin_amdgcn_s_setprio(0); }

// layer-3 gate: U3' = U_3 * RX(x[12+w])  (ABCD closed form)
__device__ __forceinline__ void load_gate3(const float4* __restrict__ U3w,
                                           const float2* __restrict__ cs12,
                                           int w, f32x2& ab, f32x2& cd) {
    float4 g = U3w[w];
    float2 sc = cs12[w];
    float c = sc.x, s = sc.y;
    float A = g.x * c + g.w * s;
    float B = g.y * c - g.z * s;
    float C = g.z * c + g.y * s;
    float D = g.w * c - g.x * s;
    ab = f32x2{A, B}; cd = f32x2{C, D};
}

// ---- prep1: encode cos/sin + ZYZ of ansatz blocks (+ raw ABCD of block 3)
__global__ void prep1_kernel(const float* __restrict__ x,
                             const float* __restrict__ wts,
                             float2* __restrict__ ys,         // 72 (cy,sy); row 3 unused
                             float2* __restrict__ cdah,       // 72 (c/2, d/2); row 3 unused
                             float4* __restrict__ U3w,        // 12 ABCD of block 3
                             float2* __restrict__ cs,         // B*24
                             int total)
{
    int idx = blockIdx.x * blockDim.x + threadIdx.x;
    if (idx < total) {
        float th = 0.5f * x[idx];
        float s, c; sincosf(th, &s, &c);
        cs[idx] = make_float2(c, s);
    }
    if (idx < 72) {
        int ab = idx / 12, w = idx % 12;
        float a  = 0.5f * wts[(ab * 3 + 0) * 12 + w];
        float bb = 0.5f * wts[(ab * 3 + 1) * 12 + w];
        float g  = 0.5f * wts[(ab * 3 + 2) * 12 + w];
        float sa, ca, sb, cb, sg, cg;
        sincosf(a,  &sa, &ca);
        sincosf(bb, &sb, &cb);
        sincosf(g,  &sg, &cg);
        float A = cb * (ca * cg - sa * sg);
        float B = sb * (ca * cg + sa * sg);
        float C = cb * (sa * cg + ca * sg);
        float D = sb * (sa * cg - ca * sg);
        if (ab == 3) U3w[w] = make_float4(A, B, C, D);
        float cy = sqrtf(A * A + B * B);
        float sy = sqrtf(C * C + D * D);
        float f00 = atan2f(-B, A);
        float f10 = atan2f(D, C);
        ys[idx]   = make_float2(cy, sy);
        cdah[idx] = make_float2(0.5f * (f10 - f00), -0.5f * (f10 + f00));
    }
}

// ---- prep2: 6 diagonal tables E_l(k), applied at P0 of layer l
// E_0=D0; E_1=D1*C0(sig); E_2=D2*C1(sig); E_3=C2(sig) (layer3 = full ABCD gate);
// E_4=D4; E_5=D5*C4(sig); C5 vanishes in |.|^2
__global__ void prep2_kernel(const float2* __restrict__ cdah,
                             float2* __restrict__ tabs)       // 6*4096
{
    int idx = blockIdx.x * blockDim.x + threadIdx.x;
    if (idx >= 6 * NS) return;
    int tl = idx >> 12, k = idx & (NS - 1);
    int sk = ring_sigma_c(k);
    float ph = 0.f;
    for (int w = 0; w < 12; ++w) {
        float zd = ((k  >> (11 - w)) & 1) ? 1.f : -1.f;
        float zc = ((sk >> (11 - w)) & 1) ? 1.f : -1.f;
        float dcf = 0.f, ccf = 0.f;
        if (tl == 0)      { dcf = cdah[0 * 12 + w].y; }
        else if (tl == 1) { dcf = cdah[1 * 12 + w].y; ccf = cdah[0 * 12 + w].x; }
        else if (tl == 2) { dcf = cdah[2 * 12 + w].y; ccf = cdah[1 * 12 + w].x; }
        else if (tl == 3) { ccf = cdah[2 * 12 + w].x; }
        else if (tl == 4) { dcf = cdah[4 * 12 + w].y; }
        else              { dcf = cdah[5 * 12 + w].y; ccf = cdah[4 * 12 + w].x; }
        ph += zd * dcf + zc * ccf;
    }
    float s, c; sincosf(ph, &s, &c);
    tabs[idx] = make_float2(c, s);
}

// Phase maps (thread t: 9 bits, reg r: 3 bits):
// P0: k=(r<<9)|t               wires 0,1,2   (cross-wave -> barrier)
// P1: k=t[8:6]<<9|r<<6|t[5:0]  wires 3,4,5   (wave-private -> fence)
// P2: k=t[8:3]<<6|r<<3|t[2:0]  wires 6,7,8   (wave-private -> fence)
// P3: k=(t<<3)|r               wires 9,10,11; ring scatter (cross-wave -> barriers)
__global__ __launch_bounds__(NT, 1)
void tqhea_kernel(const float2* __restrict__ ys,    // 72 (cy,sy)
                  const float2* __restrict__ cs,    // (B,24)
                  const f32x2*  __restrict__ tabs,  // 6*4096 diag tables
                  const float4* __restrict__ U3w,   // 12 ABCD (block 3)
                  float* __restrict__ out)          // (B,1)
{
    __shared__ f32x2 psi[NS];        // 32 KB, swz-swizzled

    const int b = blockIdx.x;
    const int t = threadIdx.x;       // 0..511

    const int tsw = swz(t);                          // P0: idx = (r<<9)|tsw
    const int sQt = swz(ring_pi_c(t << 3));          // scatter: idx = sQt ^ pi(r)
    const int Pt  = ring_pi_c(t << 3);               // reduction diag base

    const float2* csb  = cs + b * 24;
    const float2* cs12 = csb + 12;

    // ---- init: |0..0> + first RX layer = product state (write-only, P0 map)
    {
        float2 rc[12];
        #pragma unroll
        for (int i = 0; i < 12; ++i) rc[i] = csb[i];
        float mlan = 1.f;
        #pragma unroll
        for (int bit = 0; bit < 9; ++bit)            // t bit b <-> wire 11-b
            mlan *= ((t >> bit) & 1) ? rc[11 - bit].y : rc[11 - bit].x;
        int q = __popc(t);
        #pragma unroll
        for (int r = 0; r < 8; ++r) {
            float mr = 1.f;
            #pragma unroll
            for (int p = 0; p < 3; ++p)              // r bit p <-> wire 2-p
                mr *= ((r >> p) & 1) ? rc[2 - p].y : rc[2 - p].x;
            float mag = mr * mlan;
            int pc = (q + __popc(r)) & 3;            // (-i)^popcount phase
            f32x2 v;
            v.x = (pc == 0) ? mag : ((pc == 2) ? -mag : 0.f);
            v.y = (pc == 1) ? -mag : ((pc == 3) ? mag : 0.f);
            psi[(r << 9) | tsw] = v;
        }
    }

    // preload layer-0 diagonal table
    f32x2 e[8];
    #pragma unroll
    for (int r = 0; r < 8; ++r) e[r] = tabs[(r << 9) + t];
    __syncthreads();

    float acc = 0.f;

    #pragma unroll 1
    for (int lay = 0; lay < 6; ++lay) {
        const bool full = (lay == 3);                // block 3 = full ABCD gates (RX folded)
        const float2* yrow = ys + lay * 12;
        f32x2 a[8];

        // ---- P0: wires 0..2; diagonal first, then prefetch next layer's table
        #pragma unroll
        for (int r = 0; r < 8; ++r) a[r] = psi[(r << 9) | tsw];
        prio_hi();
        #pragma unroll
        for (int r = 0; r < 8; ++r) cdiag(e[r], a[r]);
        prio_lo();
        if (lay < 5) {
            #pragma unroll
            for (int r = 0; r < 8; ++r) e[r] = tabs[(lay + 1) * NS + (r << 9) + t];
        }
        prio_hi();
        if (full) {
            f32x2 gab, gcd;
            load_gate3(U3w, cs12, 0, gab, gcd); cgate8<2>(a, gab, gcd);
            load_gate3(U3w, cs12, 1, gab, gcd); cgate8<1>(a, gab, gcd);
            load_gate3(U3w, cs12, 2, gab, gcd); cgate8<0>(a, gab, gcd);
        } else {
            ygate8<2>(a, yrow[0]);
            ygate8<1>(a, yrow[1]);
            ygate8<0>(a, yrow[2]);
        }
        prio_lo();
        #pragma unroll
        for (int r = 0; r < 8; ++r) psi[(r << 9) | tsw] = a[r];
        __syncthreads();                 // P0 writes are cross-wave-slice

        // ---- P1: wires 3..5 (wave-private)
        int a1[8];
        #pragma unroll
        for (int r = 0; r < 8; ++r)
            a1[r] = swz(((t >> 6) << 9) | (r << 6) | (t & 63));
        #pragma unroll
        for (int r = 0; r < 8; ++r) a[r] = psi[a1[r]];
        prio_hi();
        if (full) {
            f32x2 gab, gcd;
            load_gate3(U3w, cs12, 3, gab, gcd); cgate8<2>(a, gab, gcd);
            load_gate3(U3w, cs12, 4, gab, gcd); cgate8<1>(a, gab, gcd);
            load_gate3(U3w, cs12, 5, gab, gcd); cgate8<0>(a, gab, gcd);
        } else {
            ygate8<2>(a, yrow[3]);
            ygate8<1>(a, yrow[4]);
            ygate8<0>(a, yrow[5]);
        }
        prio_lo();
        #pragma unroll
        for (int r = 0; r < 8; ++r) psi[a1[r]] = a[r];
        wave_lds_fence();

        // ---- P2: wires 6..8 (wave-private)
        int a2[8];
        #pragma unroll
        for (int r = 0; r < 8; ++r)
            a2[r] = swz(((t >> 3) << 6) | (r << 3) | (t & 7));
        #pragma unroll
        for (int r = 0; r < 8; ++r) a[r] = psi[a2[r]];
        prio_hi();
        if (full) {
            f32x2 gab, gcd;
            load_gate3(U3w, cs12, 6, gab, gcd); cgate8<2>(a, gab, gcd);
            load_gate3(U3w, cs12, 7, gab, gcd); cgate8<1>(a, gab, gcd);
            load_gate3(U3w, cs12, 8, gab, gcd); cgate8<0>(a, gab, gcd);
        } else {
            ygate8<2>(a, yrow[6]);
            ygate8<1>(a, yrow[7]);
            ygate8<0>(a, yrow[8]);
        }
        prio_lo();
        #pragma unroll
        for (int r = 0; r < 8; ++r) psi[a2[r]] = a[r];
        wave_lds_fence();

        // ---- P3: wires 9..11; thread t, reg r hold k=(t<<3)|r
        const int base3 = swz(t << 3);               // XOR addressing
        #pragma unroll
        for (int r = 0; r < 8; ++r) a[r] = psi[base3 ^ r];
        prio_hi();
        if (full) {
            f32x2 gab, gcd;
            load_gate3(U3w, cs12, 9,  gab, gcd); cgate8<2>(a, gab, gcd);
            load_gate3(U3w, cs12, 10, gab, gcd); cgate8<1>(a, gab, gcd);
            load_gate3(U3w, cs12, 11, gab, gcd); cgate8<0>(a, gab, gcd);
        } else {
            ygate8<2>(a, yrow[9]);
            ygate8<1>(a, yrow[10]);
            ygate8<0>(a, yrow[11]);
        }
        prio_lo();
        if (lay == 5) {
            // ---- <H>: final ring via pi; diag = 12 - 2*popc(pi(k))
            #pragma unroll
            for (int r = 0; r < 8; ++r) {
                float d = 12.0f - 2.0f * (float)__popc(Pt ^ ring_pi_c(r));
                acc += (a[r].x * a[r].x + a[r].y * a[r].y) * d;
            }
        } else {
            __syncthreads();    // WAR: all waves' P3 reads done before ring scatter
            #pragma unroll
            for (int r = 0; r < 8; ++r) psi[sQt ^ ring_pi_c(r)] = a[r];
            __syncthreads();
        }
    }

    // ---- reduce: per-wave shfl, cross-wave via psi reuse
    #pragma unroll
    for (int off = 32; off > 0; off >>= 1)
        acc += __shfl_down(acc, off);
    __syncthreads();                       // all psi reads done; safe to reuse
    if ((t & 63) == 0) ((float*)psi)[t >> 6] = acc;
    __syncthreads();
    if (t == 0) {
        const float* rb = (const float*)psi;
        out[b] = rb[0] + rb[1] + rb[2] + rb[3] + rb[4] + rb[5] + rb[6] + rb[7];
    }
}

extern "C" void kernel_launch(void* const* d_in, const int* in_sizes, int n_in,
                              void* d_out, int out_size, void* d_ws, size_t ws_size,
                              hipStream_t stream) {
    const float* x   = (const float*)d_in[0];   // (B, 24) float32
    const float* wts = (const float*)d_in[1];   // (6, 3, 12) float32
    float* out = (float*)d_out;                 // (B, 1) float32
    int B = in_sizes[0] / 24;
    int total = B * 24;

    char* ws = (char*)d_ws;
    float2* ys   = (float2*)(ws);                         // 576 B
    float2* cdah = (float2*)(ws + 576);                   // 576 B
    float4* U3w  = (float4*)(ws + 1152);                  // 192 B
    float2* cs   = (float2*)(ws + 1344);                  // B*24*8
    float2* tabs = (float2*)(ws + 1344 + (size_t)total * 8);  // 6*4096*8

    prep1_kernel<<<dim3((total + NTP - 1) / NTP), dim3(NTP), 0, stream>>>(x, wts, ys, cdah, U3w, cs, total);
    prep2_kernel<<<dim3((6 * NS + NTP - 1) / NTP), dim3(NTP), 0, stream>>>(cdah, tabs);
    tqhea_kernel<<<dim3(B), dim3(NT), 0, stream>>>(ys, cs, (const f32x2*)tabs, U3w, out);
}